// Round 19
// baseline (105.802 us; speedup 1.0000x reference)
//
#include <hip/hip_runtime.h>
#include <hip/hip_bf16.h>

// SubjectLayers via bf16 MFMA 32x32x16: out[b,o,t] = sum_c W[s,o,c]*x[b,c,t] + b[s,o]
// B=128, C=64, T=8192, S=16. fp32 in/out, bf16 matrix cores.
//
// R13 (3rd resubmit after infra failures): reg-staged T14 pipeline
// (issue-early / write-late), 4 c-quarters.
//  - R12 showed intra-block stage/compute overlap is the live lever (+3.4%),
//    but global_load_lds retires only at barrier drains -> first half always
//    exposed. Reg-staging retires loads into VGPRs; the counted vmcnt sits
//    before the ds_write, which we place AFTER the previous quarter's compute.
//  - bf16 LDS tile [64][256] = 32KB; quarter = 16 c-rows (16KB f32 loads).
//  - per iter: {issue Q(i) loads (4x 1KB-row float4/wave, 16 VGPR transient)
//      -> compute Q(i-1) (16 u16 frag reads x2st, 4 MFMAs) -> cvt+ds_write Q(i)
//      -> __syncthreads (vmcnt already retired -> drain free)}
//  - only Q0's 16KB is exposed (vs 32KB in R12); stores direct from acc
//    (R10-proven clean full-line shape); acc[2][2] f32x16 static-indexed.

typedef __attribute__((ext_vector_type(8))) short  bf16x8;   // 4 VGPRs
typedef __attribute__((ext_vector_type(16))) float f32x16;   // 16 VGPRs

namespace {
constexpr int Cdim  = 64;
constexpr int Tdim  = 8192;
constexpr int TT    = 256;        // t per block tile
constexpr int BLOCK = 256;        // 4 waves
}

static __device__ __forceinline__ unsigned short f2bfu(float f) {
    return __builtin_bit_cast(unsigned short, __float2bfloat16(f));
}

__global__ __launch_bounds__(BLOCK, 2)
void subject_layers_r13(const float* __restrict__ x,
                        const int*   __restrict__ subj,
                        const float* __restrict__ W,
                        const float* __restrict__ bias,
                        float*       __restrict__ out) {
    __shared__ unsigned short tile[Cdim * TT];   // 32 KB bf16

    const int b    = blockIdx.y;
    const int tb   = blockIdx.x;
    const int tid  = threadIdx.x;
    const int wave = tid >> 6;
    const int lane = tid & 63;
    const int hi   = lane >> 5;   // 0..1
    const int ln   = lane & 31;   // m/n index within 32-tile
    const int s    = subj[b];

    const size_t xbase = (size_t)b * Cdim * Tdim + (size_t)tb * TT;

    // ---- quarter staging: quarter q = c-rows q*16..q*16+15;
    //      wave stages rows q*16 + g*4 + wave (g<4), one 1KB row burst each ----
    float4 v[4];

    // prologue: issue Q0 loads (fly under afrag/bini setup)
    #pragma unroll
    for (int g = 0; g < 4; ++g) {
        const int row = 0 * 16 + g * 4 + wave;
        v[g] = *reinterpret_cast<const float4*>(x + xbase + (size_t)row * Tdim + lane * 4);
    }

    // ---- A fragments: W[s] -> bf16 ----
    // A[m][k]: m = ln, k = kb*16 + hi*8 + j  (mirrored with B -> k-perm cancels)
    bf16x8 afrag[2][4];
    const float* Wb = W + (size_t)s * Cdim * Cdim;
    #pragma unroll
    for (int ot = 0; ot < 2; ++ot) {
        #pragma unroll
        for (int kb = 0; kb < 4; ++kb) {
            const float* ap = Wb + (size_t)(ot * 32 + ln) * Cdim + kb * 16 + hi * 8;
            const float4 a0 = *reinterpret_cast<const float4*>(ap);
            const float4 a1 = *reinterpret_cast<const float4*>(ap + 4);
            bf16x8 f;
            f[0] = (short)f2bfu(a0.x); f[1] = (short)f2bfu(a0.y);
            f[2] = (short)f2bfu(a0.z); f[3] = (short)f2bfu(a0.w);
            f[4] = (short)f2bfu(a1.x); f[5] = (short)f2bfu(a1.y);
            f[6] = (short)f2bfu(a1.z); f[7] = (short)f2bfu(a1.w);
            afrag[ot][kb] = f;
        }
    }

    // ---- bias -> accumulator init (acc lives across all barriers) ----
    // C/D: col = ln, row(reg r) = (r&3) + 8*(r>>2) + 4*hi   [m74/m101-verified]
    f32x16 acc[2][2];   // [st][ot]
    {
        const float* bb = bias + (size_t)s * Cdim;
        #pragma unroll
        for (int ot = 0; ot < 2; ++ot) {
            f32x16 bi;
            #pragma unroll
            for (int r = 0; r < 16; ++r)
                bi[r] = bb[ot * 32 + (r & 3) + 8 * (r >> 2) + 4 * hi];
            acc[0][ot] = bi;
            acc[1][ot] = bi;
        }
    }

    // write Q0 (counted vmcnt lands here), barrier
    #pragma unroll
    for (int g = 0; g < 4; ++g) {
        const int row = 0 * 16 + g * 4 + wave;
        ushort4 u;
        u.x = f2bfu(v[g].x); u.y = f2bfu(v[g].y);
        u.z = f2bfu(v[g].z); u.w = f2bfu(v[g].w);
        *reinterpret_cast<ushort4*>(&tile[row * TT + lane * 4]) = u;
    }
    __syncthreads();   // Q0 ready (loads already retired -> drain cheap)

    // ---- pipelined quarters: issue Q(q) -> compute Q(q-1) -> write Q(q) -> bar
    #pragma unroll
    for (int q = 1; q < 4; ++q) {
        // issue loads for quarter q (fly under compute below)
        #pragma unroll
        for (int g = 0; g < 4; ++g) {
            const int row = q * 16 + g * 4 + wave;
            v[g] = *reinterpret_cast<const float4*>(x + xbase + (size_t)row * Tdim + lane * 4);
        }

        // compute quarter q-1 (kb = q-1)
        #pragma unroll
        for (int st = 0; st < 2; ++st) {
            const int col = wave * 64 + st * 32 + ln;
            bf16x8 f;
            #pragma unroll
            for (int j = 0; j < 8; ++j)
                f[j] = (short)tile[((q - 1) * 16 + hi * 8 + j) * TT + col];
            #pragma unroll
            for (int ot = 0; ot < 2; ++ot)
                acc[st][ot] = __builtin_amdgcn_mfma_f32_32x32x16_bf16(
                    afrag[ot][q - 1], f, acc[st][ot], 0, 0, 0);
        }

        // write quarter q (vmcnt waits here, hidden by compute above)
        #pragma unroll
        for (int g = 0; g < 4; ++g) {
            const int row = q * 16 + g * 4 + wave;
            ushort4 u;
            u.x = f2bfu(v[g].x); u.y = f2bfu(v[g].y);
            u.z = f2bfu(v[g].z); u.w = f2bfu(v[g].w);
            *reinterpret_cast<ushort4*>(&tile[row * TT + lane * 4]) = u;
        }
        __syncthreads();
    }

    // ---- final quarter compute (kb=3) + direct-acc stores ----
    float* ob = out + xbase;
    #pragma unroll
    for (int st = 0; st < 2; ++st) {
        const int col = wave * 64 + st * 32 + ln;
        bf16x8 f;
        #pragma unroll
        for (int j = 0; j < 8; ++j)
            f[j] = (short)tile[(3 * 16 + hi * 8 + j) * TT + col];
        #pragma unroll
        for (int ot = 0; ot < 2; ++ot) {
            acc[st][ot] = __builtin_amdgcn_mfma_f32_32x32x16_bf16(
                afrag[ot][3], f, acc[st][ot], 0, 0, 0);
            // store instr r: 2 rows x 128B full aligned lines (R10-proven clean)
            #pragma unroll
            for (int r = 0; r < 16; ++r)
                ob[(size_t)(ot * 32 + (r & 3) + 8 * (r >> 2) + 4 * hi) * Tdim + col]
                    = acc[st][ot][r];
        }
    }
}

extern "C" void kernel_launch(void* const* d_in, const int* in_sizes, int n_in,
                              void* d_out, int out_size, void* d_ws, size_t ws_size,
                              hipStream_t stream) {
    const float* x    = (const float*)d_in[0];   // [B, C, T]
    const int*   subj = (const int*)  d_in[1];   // [B]
    const float* W    = (const float*)d_in[2];   // [S, C, C]
    const float* bias = (const float*)d_in[3];   // [S, C]
    float*       out  = (float*)d_out;           // [B, C, T]

    const int B = in_sizes[1];                   // 128
    dim3 grid(Tdim / TT, B);                     // (32, 128) = 4096 blocks
    dim3 block(BLOCK);
    hipLaunchKernelGGL(subject_layers_r13, grid, block, 0, stream,
                       x, subj, W, bias, out);
}

// Round 20
// 104.805 us; speedup vs baseline: 1.0095x; 1.0095x over previous
//
#include <hip/hip_runtime.h>
#include <hip/hip_bf16.h>

// SubjectLayers via bf16 MFMA 32x32x16: out[b,o,t] = sum_c W[s,o,c]*x[b,c,t] + b[s,o]
// B=128, C=64, T=8192, S=16. fp32 in/out, bf16 matrix cores.
//
// R14 = R12 (gload_lds staging, C-split, direct-acc stores; best 101.0us)
//       with counted-vmcnt barriers instead of __syncthreads (T4):
//  - issue ALL 16 gload_lds per wave upfront (quarter-ordered, disjoint rows)
//  - per quarter q: s_waitcnt vmcnt(12-4q) + raw s_barrier + sched_barrier(0)
//    -> only quarter q's DMA is waited on; Q(q+1..3) stay in flight across
//    the barrier (syncthreads would drain vmcnt(0) = R12's residual exposure)
//  - correctness: vmem retirement is in-order (m135); at vmcnt(12-4q) the
//    outstanding ops are the youngest <=12-4q, and Q(q)'s last DMA always has
//    >=12-4q younger ops (the later staging), so it is retired -- under ANY
//    compiler placement of the W/bias loads (all issued before the waits).
//  - compute/store per quarter unchanged from R12 (frag cvt reads, 4 MFMAs,
//    clean full-line direct-acc stores in q==3).

typedef __attribute__((ext_vector_type(8))) short  bf16x8;   // 4 VGPRs
typedef __attribute__((ext_vector_type(16))) float f32x16;   // 16 VGPRs

namespace {
constexpr int Cdim  = 64;
constexpr int Tdim  = 8192;
constexpr int TT    = 256;        // t per block tile
constexpr int BLOCK = 256;        // 4 waves
}

static __device__ __forceinline__ short f2bf(float f) {
    return (short)__builtin_bit_cast(unsigned short, __float2bfloat16(f));
}

__global__ __launch_bounds__(BLOCK, 2)
void subject_layers_r14(const float* __restrict__ x,
                        const int*   __restrict__ subj,
                        const float* __restrict__ W,
                        const float* __restrict__ bias,
                        float*       __restrict__ out) {
    __shared__ float tile[Cdim * TT];   // 64 KB f32; written once by DMA

    const int b    = blockIdx.y;
    const int tb   = blockIdx.x;
    const int tid  = threadIdx.x;
    const int wave = tid >> 6;
    const int lane = tid & 63;
    const int hi   = lane >> 5;   // 0..1
    const int ln   = lane & 31;   // m/n index within 32-tile
    const int s    = subj[b];

    const size_t xbase = (size_t)b * Cdim * Tdim + (size_t)tb * TT;

    // ---- issue ALL staging DMA upfront, quarter-ordered ----
    // quarter q rows: q*16 + g*4 + wave (g<4); one gload_lds = one 1KB row.
    #pragma unroll
    for (int q = 0; q < 4; ++q) {
        #pragma unroll
        for (int g = 0; g < 4; ++g) {
            const int row = q * 16 + g * 4 + wave;
            __builtin_amdgcn_global_load_lds(
                (const __attribute__((address_space(1))) unsigned int*)
                    (x + xbase + (size_t)row * Tdim + lane * 4),
                (__attribute__((address_space(3))) unsigned int*)
                    (&tile[row * TT]),
                16, 0, 0);
        }
    }

    // ---- A fragments: W[s] -> bf16 (L2-hot; flies under the DMA) ----
    // A[m][k]: m = ln, k = kb*16 + hi*8 + j  (mirrored with B -> k-perm cancels)
    bf16x8 afrag[2][4];
    const float* Wb = W + (size_t)s * Cdim * Cdim;
    #pragma unroll
    for (int ot = 0; ot < 2; ++ot) {
        #pragma unroll
        for (int kb = 0; kb < 4; ++kb) {
            const float* ap = Wb + (size_t)(ot * 32 + ln) * Cdim + kb * 16 + hi * 8;
            const float4 a0 = *reinterpret_cast<const float4*>(ap);
            const float4 a1 = *reinterpret_cast<const float4*>(ap + 4);
            bf16x8 f;
            f[0] = f2bf(a0.x); f[1] = f2bf(a0.y); f[2] = f2bf(a0.z); f[3] = f2bf(a0.w);
            f[4] = f2bf(a1.x); f[5] = f2bf(a1.y); f[6] = f2bf(a1.z); f[7] = f2bf(a1.w);
            afrag[ot][kb] = f;
        }
    }

    // ---- bias -> accumulator init ----
    // C/D: col = ln, row(reg r) = (r&3) + 8*(r>>2) + 4*hi   [m74/m101-verified]
    f32x16 acc[2][2];   // [st][ot]
    {
        const float* bb = bias + (size_t)s * Cdim;
        #pragma unroll
        for (int ot = 0; ot < 2; ++ot) {
            f32x16 bi;
            #pragma unroll
            for (int r = 0; r < 16; ++r)
                bi[r] = bb[ot * 32 + (r & 3) + 8 * (r >> 2) + 4 * hi];
            acc[0][ot] = bi;
            acc[1][ot] = bi;
        }
    }

    // ---- quarter loop: counted-vmcnt barrier, then compute quarter q ----
    float* ob = out + xbase;
    #pragma unroll
    for (int q = 0; q < 4; ++q) {
        // wait ONLY for quarter q's DMA (12-4q younger staging ops may remain)
        if (q == 0)      asm volatile("s_waitcnt vmcnt(12)" ::: "memory");
        else if (q == 1) asm volatile("s_waitcnt vmcnt(8)"  ::: "memory");
        else if (q == 2) asm volatile("s_waitcnt vmcnt(4)"  ::: "memory");
        else             asm volatile("s_waitcnt vmcnt(0)"  ::: "memory");
        __builtin_amdgcn_s_barrier();
        __builtin_amdgcn_sched_barrier(0);   // pin: no ds_read hoisted above

        // compute quarter q (kb = q): 2 t-steps x 2 o-tiles
        #pragma unroll
        for (int st = 0; st < 2; ++st) {
            const int col = wave * 64 + st * 32 + ln;
            bf16x8 f;
            #pragma unroll
            for (int j = 0; j < 8; ++j)
                f[j] = f2bf(tile[(q * 16 + hi * 8 + j) * TT + col]);
            #pragma unroll
            for (int ot = 0; ot < 2; ++ot)
                acc[st][ot] = __builtin_amdgcn_mfma_f32_32x32x16_bf16(
                    afrag[ot][q], f, acc[st][ot], 0, 0, 0);
        }

        // last quarter: stores direct from acc (2 rows x 128B full lines each)
        if (q == 3) {
            #pragma unroll
            for (int st = 0; st < 2; ++st) {
                const int col = wave * 64 + st * 32 + ln;
                #pragma unroll
                for (int ot = 0; ot < 2; ++ot)
                    #pragma unroll
                    for (int r = 0; r < 16; ++r)
                        ob[(size_t)(ot * 32 + (r & 3) + 8 * (r >> 2) + 4 * hi) * Tdim + col]
                            = acc[st][ot][r];
            }
        }
    }
}

extern "C" void kernel_launch(void* const* d_in, const int* in_sizes, int n_in,
                              void* d_out, int out_size, void* d_ws, size_t ws_size,
                              hipStream_t stream) {
    const float* x    = (const float*)d_in[0];   // [B, C, T]
    const int*   subj = (const int*)  d_in[1];   // [B]
    const float* W    = (const float*)d_in[2];   // [S, C, C]
    const float* bias = (const float*)d_in[3];   // [S, C]
    float*       out  = (float*)d_out;           // [B, C, T]

    const int B = in_sizes[1];                   // 128
    dim3 grid(Tdim / TT, B);                     // (32, 128) = 4096 blocks
    dim3 block(BLOCK);
    hipLaunchKernelGGL(subject_layers_r14, grid, block, 0, stream,
                       x, subj, W, bias, out);
}